// Round 5
// baseline (448.469 us; speedup 1.0000x reference)
//
#include <hip/hip_runtime.h>
#include <math.h>

#define Bc  32
#define Hc  8
#define LQc 256
#define LVc 1024
#define Dc  512

typedef short bf16x8 __attribute__((ext_vector_type(8)));
typedef float f32x4  __attribute__((ext_vector_type(4)));

__device__ __forceinline__ unsigned short f2bf(float x) {   // RNE fp32->bf16
    unsigned u = __builtin_bit_cast(unsigned, x);
    u = (u + 0x7fffu + ((u >> 16) & 1u)) >> 16;
    return (unsigned short)u;
}

__device__ __forceinline__ void gload16(const ushort* g, ushort* l) {
    __builtin_amdgcn_global_load_lds(
        (const __attribute__((address_space(1))) unsigned*)g,
        (__attribute__((address_space(3))) unsigned*)l, 16, 0, 0);
}

__device__ __forceinline__ bf16x8 pack8(float4 a, float4 b) {
    bf16x8 r;
    r[0] = (short)f2bf(a.x); r[1] = (short)f2bf(a.y);
    r[2] = (short)f2bf(a.z); r[3] = (short)f2bf(a.w);
    r[4] = (short)f2bf(b.x); r[5] = (short)f2bf(b.y);
    r[6] = (short)f2bf(b.z); r[7] = (short)f2bf(b.w);
    return r;
}

// ---------------------------------------------------------------------------
// All 5 weight matrices (each 262144 floats) -> bf16, consecutive dst regions
// ---------------------------------------------------------------------------
__global__ __launch_bounds__(256) void cvt_w(const float* __restrict__ a,
                                             const float* __restrict__ b,
                                             const float* __restrict__ c,
                                             const float* __restrict__ d,
                                             const float* __restrict__ e,
                                             ushort* __restrict__ out) {
    const int i = blockIdx.x * 256 + threadIdx.x;    // [0, 327680)
    const int t = i >> 16, j = i & 65535;
    const float* src = (t == 0) ? a : (t == 1) ? b : (t == 2) ? c : (t == 3) ? d : e;
    float4 v = ((const float4*)src)[j];
    ushort4 o;
    o.x = f2bf(v.x); o.y = f2bf(v.y); o.z = f2bf(v.z); o.w = f2bf(v.w);
    ((ushort4*)(out + (size_t)t * 262144))[j] = o;
}

// ---------------------------------------------------------------------------
// fp32 [b][L][D] -> bf16 [b][D][L] transpose+convert, 32x32 LDS tiles
// ---------------------------------------------------------------------------
__global__ __launch_bounds__(256) void transpose_cvt(const float* __restrict__ in,
                                                     ushort* __restrict__ out,
                                                     int L, int D) {
    __shared__ float t[32][33];
    const int b = blockIdx.z;
    const int l0 = blockIdx.x * 32, d0 = blockIdx.y * 32;
    in  += (size_t)b * L * D;
    out += (size_t)b * L * D;
    const int r = threadIdx.x >> 5, c = threadIdx.x & 31;
#pragma unroll
    for (int i = 0; i < 4; i++)
        t[r + 8 * i][c] = in[(size_t)(l0 + r + 8 * i) * D + d0 + c];
    __syncthreads();
#pragma unroll
    for (int i = 0; i < 4; i++)
        out[(size_t)(d0 + r + 8 * i) * L + l0 + c] = f2bf(t[c][r + 8 * i]);
}

// ---------------------------------------------------------------------------
// C[m,n] = alpha * sum_k A[m,k]*B[n,k] (+ bias[m])      (bf16 MFMA, f32 accum)
// 128x128 tile, BK=32, 4 waves (2x2), 4x4 16x16x32 frags per wave.
// LDS tiles use conflict-free CHUNKED layout: group g (16 rows), chunk c,
// row r, 16B granule at  g*1024 + c*256 + r*16  bytes. Lane l stages
// (row = l&15, chunk = l>>4) so gload_lds's linear lane x 16B dest matches.
// AF32: A operand is fp32 in global (staged fp32, cvt to bf16 after ds_read).
// STORE: 0 = f32 row-major, 1 = bf16 row-major, 2 = bf16 transposed
//        (256-row batches: out[(m>>8)][n][m&255], for v1^T)
// SWIZ:  1 = 1D grid, XCD-grouped decode
// ---------------------------------------------------------------------------
template <int STORE, bool BIAS, int SWIZ, bool AF32>
__global__ __launch_bounds__(256) void gemm_bt(const void* __restrict__ Av,
                                               const ushort* __restrict__ B,
                                               void* __restrict__ Cv,
                                               const float* __restrict__ bias,
                                               int M, int N, int K, float alpha,
                                               long sA, long sB, long sC,
                                               int byPerXcd) {
    __shared__ __align__(16) char AsRaw[AF32 ? 16384 : 8192];
    __shared__ __align__(16) ushort Bs[4096];
    ushort* Ash = (ushort*)AsRaw;
    float*  Asf = (float*)AsRaw;

    const int z = blockIdx.z;
    const ushort* Ah = (const ushort*)Av + (size_t)z * sA;
    const float*  Af = (const float*)Av  + (size_t)z * sA;
    B += (size_t)z * sB;
    float*  Cf = (float*)Cv  + (size_t)z * sC;
    ushort* Ch = (ushort*)Cv + (size_t)z * sC;

    int bm, bn;
    if constexpr (SWIZ) {
        const int bid = blockIdx.x;
        const int xcd = bid & 7, slot = bid >> 3;
        bm = (xcd * byPerXcd + (slot >> 2)) * 128;
        bn = (slot & 3) * 128;
    } else {
        bm = blockIdx.y * 128;
        bn = blockIdx.x * 128;
    }
    const int tid = threadIdx.x;
    const int wave = tid >> 6, l = tid & 63;
    const int wm = (wave >> 1) * 64, wn = (wave & 1) * 64;
    const int l15 = l & 15, lh = l >> 4;

    f32x4 acc[4][4];
#pragma unroll
    for (int m = 0; m < 4; m++)
#pragma unroll
        for (int n = 0; n < 4; n++) acc[m][n] = (f32x4){0.f, 0.f, 0.f, 0.f};

    // staging base pointers (lane-permuted source)
    const ushort* gB0 = B + (size_t)(bn + wave * 16 + l15) * K + lh * 8;
    const ushort* gAh0 = Ah + (size_t)(bm + wave * 16 + l15) * K + lh * 8;
    const float*  gAf0 = Af + (size_t)(bm + wave * 16 + l15) * K + lh * 4;

    for (int k0 = 0; k0 < K; k0 += 32) {
        if constexpr (AF32) {
            const float* p = gAf0 + k0;
            float* d = Asf + wave * 512;
            gload16((const ushort*)p,                      (ushort*)d);
            gload16((const ushort*)(p + 16),               (ushort*)(d + 256));
            gload16((const ushort*)(p + (size_t)64 * K),   (ushort*)(d + 2048));
            gload16((const ushort*)(p + (size_t)64 * K + 16), (ushort*)(d + 2304));
        } else {
            gload16(gAh0 + k0,                   Ash + wave * 512);
            gload16(gAh0 + k0 + (size_t)64 * K,  Ash + (wave + 4) * 512);
        }
        gload16(gB0 + k0,                  Bs + wave * 512);
        gload16(gB0 + k0 + (size_t)64 * K, Bs + (wave + 4) * 512);
        __syncthreads();

        bf16x8 af[4], bfr[4];
#pragma unroll
        for (int m = 0; m < 4; m++) {
            if constexpr (AF32) {
                const float* fb = Asf + ((wm >> 4) + m) * 512 + lh * 128 + l15 * 4;
                float4 x0 = *(const float4*)fb;
                float4 x1 = *(const float4*)(fb + 64);
                af[m] = pack8(x0, x1);
            } else {
                af[m] = *(const bf16x8*)&Ash[((wm >> 4) + m) * 512 + lh * 128 + l15 * 8];
            }
        }
#pragma unroll
        for (int n = 0; n < 4; n++)
            bfr[n] = *(const bf16x8*)&Bs[((wn >> 4) + n) * 512 + lh * 128 + l15 * 8];
#pragma unroll
        for (int m = 0; m < 4; m++)
#pragma unroll
            for (int n = 0; n < 4; n++)
                acc[m][n] = __builtin_amdgcn_mfma_f32_16x16x32_bf16(
                    af[m], bfr[n], acc[m][n], 0, 0, 0);
        __syncthreads();
    }

    if constexpr (STORE == 2) {
#pragma unroll
        for (int m = 0; m < 4; m++) {
            const int row0 = bm + wm + m * 16 + lh * 4;
            const int bb = row0 >> 8, q = row0 & 255;
#pragma unroll
            for (int n = 0; n < 4; n++) {
                const int col = bn + wn + n * 16 + l15;
                ushort4 o;
                o.x = f2bf(acc[m][n][0] * alpha);
                o.y = f2bf(acc[m][n][1] * alpha);
                o.z = f2bf(acc[m][n][2] * alpha);
                o.w = f2bf(acc[m][n][3] * alpha);
                *(ushort4*)&Ch[(size_t)bb * N * 256 + (size_t)col * 256 + q] = o;
            }
        }
    } else if constexpr (STORE == 1) {
#pragma unroll
        for (int m = 0; m < 4; m++)
#pragma unroll
            for (int r = 0; r < 4; r++) {
                const int row = bm + wm + m * 16 + lh * 4 + r;
                const float bv = BIAS ? bias[row] : 0.f;
#pragma unroll
                for (int n = 0; n < 4; n++) {
                    const int col = bn + wn + n * 16 + l15;
                    Ch[(size_t)row * N + col] = f2bf(acc[m][n][r] * alpha + bv);
                }
            }
    } else {
#pragma unroll
        for (int m = 0; m < 4; m++)
#pragma unroll
            for (int r = 0; r < 4; r++) {
                const int row = bm + wm + m * 16 + lh * 4 + r;
                const float bv = BIAS ? bias[row] : 0.f;
#pragma unroll
                for (int n = 0; n < 4; n++) {
                    const int col = bn + wn + n * 16 + l15;
                    Cf[(size_t)row * N + col] = acc[m][n][r] * alpha + bv;
                }
            }
    }
}

// ---------------------------------------------------------------------------
// Fused attention v3: 64-row q-tile, XCD decode, chunked LDS, double-buffered.
// Block = (b, h, qt): grid 1024 = 8 XCD x (4 batch x 8 head x 4 qt). 4 waves.
// Phase A: S(64x256) = q @ K^T, dbuf {Q 4KB + K 16KB} x2; wave w owns rows
//   [16w,16w+16): sacc[16].
// Softmax in registers; unnormalized P -> LDS [64][264] bf16; rsum -> LDS.
// Phase B: out = P @ v1 via v1T; 4 d-chunks of 128, dbuf Vs [128][32] x2;
//   wave w owns d-cols [32w,32w+32). 1 barrier/iter. LDS 50432 B (3 blk/CU).
// ---------------------------------------------------------------------------
__global__ __launch_bounds__(256, 3) void attn_mfma(const ushort* __restrict__ qb,
                                                    const ushort* __restrict__ k1,
                                                    const ushort* __restrict__ v1T,
                                                    const int* __restrict__ vlen,
                                                    ushort* __restrict__ aout) {
    __shared__ __align__(16) char pool[50432];
    ushort* Ps = (ushort*)pool;                 // [64][264]  0..33792 B (phase B)
    float*  rs = (float*)(pool + 33792);        // [64] row sums

    const int bid = blockIdx.x;
    const int xcd = bid & 7, pos = bid >> 3;
    const int b = xcd * 4 + (pos >> 5);
    const int inner = pos & 31;
    const int h = inner >> 2, qt = inner & 3;
    const int n = b * 8 + h, q0 = qt * 64;

    const int tid = threadIdx.x, wave = tid >> 6, l = tid & 63;
    const int l15 = l & 15, lh = l >> 4;
    const int sc8 = lh * 8;
    const int vl = vlen[b];

    const ushort* qbase = qb  + ((size_t)n * LQc + q0) * Dc;
    const ushort* kbase = k1  + (size_t)b * LQc * Dc;
    const ushort* vbase = v1T + (size_t)b * LQc * Dc;

    // ---- phase A: scores 64x256, dbuf ----------------------------------
    f32x4 sacc[16];
#pragma unroll
    for (int fn = 0; fn < 16; fn++) sacc[fn] = (f32x4){0.f, 0.f, 0.f, 0.f};

    auto STAGE_A = [&](int bi, int k0) {
        ushort* q_ = (ushort*)pool + bi * 10240;
        ushort* k_ = q_ + 2048;
        gload16(qbase + (size_t)(wave * 16 + l15) * Dc + k0 + sc8, q_ + wave * 512);
#pragma unroll
        for (int j = 0; j < 4; j++)
            gload16(kbase + (size_t)((j * 4 + wave) * 16 + l15) * Dc + k0 + sc8,
                    k_ + (j * 4 + wave) * 512);
    };

    STAGE_A(0, 0);
    __syncthreads();
    for (int it = 0; it < 16; ++it) {
        if (it < 15) STAGE_A((it + 1) & 1, (it + 1) * 32);
        ushort* q_ = (ushort*)pool + (it & 1) * 10240;
        ushort* k_ = q_ + 2048;
        bf16x8 aq = *(const bf16x8*)&q_[wave * 512 + lh * 128 + l15 * 8];
#pragma unroll
        for (int fn = 0; fn < 16; fn++) {
            bf16x8 bk = *(const bf16x8*)&k_[fn * 512 + lh * 128 + l15 * 8];
            sacc[fn] = __builtin_amdgcn_mfma_f32_16x16x32_bf16(aq, bk, sacc[fn], 0, 0, 0);
        }
        __syncthreads();
    }

    // ---- prefetch first V tile (overlaps softmax VALU) -------------------
    auto STAGE_V = [&](int bi, int it) {
        const int d0 = (it >> 3) * 128, l0 = (it & 7) * 32;
        ushort* v_ = (ushort*)pool + 17024 + bi * 4096;
        gload16(vbase + (size_t)(d0 + wave * 16 + l15) * LQc + l0 + sc8, v_ + wave * 512);
        gload16(vbase + (size_t)(d0 + 64 + wave * 16 + l15) * LQc + l0 + sc8,
                v_ + (wave + 4) * 512);
    };
    STAGE_V(0, 0);

    // ---- softmax: wave owns rows [16w,16w+16) ---------------------------
#pragma unroll
    for (int r = 0; r < 4; r++) {
        const int rowl = wave * 16 + lh * 4 + r;
        float v[16];
        float rmax = -3.4e38f;
#pragma unroll
        for (int fn = 0; fn < 16; fn++) {
            const int col = fn * 16 + l15;
            float s = sacc[fn][r];
            v[fn] = (col < vl) ? s : -1e6f;
            rmax = fmaxf(rmax, v[fn]);
        }
        rmax = fmaxf(rmax, __shfl_xor(rmax, 1));
        rmax = fmaxf(rmax, __shfl_xor(rmax, 2));
        rmax = fmaxf(rmax, __shfl_xor(rmax, 4));
        rmax = fmaxf(rmax, __shfl_xor(rmax, 8));
        float rsum = 0.f;
#pragma unroll
        for (int fn = 0; fn < 16; fn++) {
            v[fn] = __expf(v[fn] - rmax);
            rsum += v[fn];
        }
        rsum += __shfl_xor(rsum, 1);
        rsum += __shfl_xor(rsum, 2);
        rsum += __shfl_xor(rsum, 4);
        rsum += __shfl_xor(rsum, 8);
#pragma unroll
        for (int fn = 0; fn < 16; fn++)
            Ps[rowl * 264 + fn * 16 + l15] = f2bf(v[fn]);
        if (l15 == 0) rs[rowl] = rsum;
    }
    __syncthreads();

    // ---- phase B: out = P @ V, 4 d-chunks of 128, dbuf ------------------
    int it = 0;
    for (int d0 = 0; d0 < Dc; d0 += 128) {
        f32x4 o[4][2];
#pragma unroll
        for (int m = 0; m < 4; m++) {
            o[m][0] = (f32x4){0.f, 0.f, 0.f, 0.f};
            o[m][1] = (f32x4){0.f, 0.f, 0.f, 0.f};
        }
        for (int l0 = 0; l0 < LQc; l0 += 32, ++it) {
            if (it < 31) STAGE_V((it + 1) & 1, it + 1);
            ushort* v_ = (ushort*)pool + 17024 + (it & 1) * 4096;
            bf16x8 vb0 = *(const bf16x8*)&v_[(wave * 2 + 0) * 512 + lh * 128 + l15 * 8];
            bf16x8 vb1 = *(const bf16x8*)&v_[(wave * 2 + 1) * 512 + lh * 128 + l15 * 8];
#pragma unroll
            for (int m = 0; m < 4; m++) {
                bf16x8 pa = *(const bf16x8*)&Ps[(m * 16 + l15) * 264 + l0 + lh * 8];
                o[m][0] = __builtin_amdgcn_mfma_f32_16x16x32_bf16(pa, vb0, o[m][0], 0, 0, 0);
                o[m][1] = __builtin_amdgcn_mfma_f32_16x16x32_bf16(pa, vb1, o[m][1], 0, 0, 0);
            }
            __syncthreads();
        }
#pragma unroll
        for (int m = 0; m < 4; m++)
#pragma unroll
            for (int r = 0; r < 4; r++) {
                const int rowl = m * 16 + lh * 4 + r;
                const float rinv = 1.0f / rs[rowl];
                ushort* op = &aout[((size_t)n * LQc + q0 + rowl) * Dc + d0 + wave * 32];
                op[l15]      = f2bf(o[m][0][r] * rinv);
                op[16 + l15] = f2bf(o[m][1][r] * rinv);
            }
    }
}

// ---------------------------------------------------------------------------
extern "C" void kernel_launch(void* const* d_in, const int* in_sizes, int n_in,
                              void* d_out, int out_size, void* d_ws, size_t ws_size,
                              hipStream_t stream) {
    const float* queries    = (const float*)d_in[0];
    const float* keys       = (const float*)d_in[1];
    const float* values     = (const float*)d_in[2];
    const float* W_q        = (const float*)d_in[3];
    const float* W_k        = (const float*)d_in[4];
    const float* W_v        = (const float*)d_in[5];
    const float* W_o        = (const float*)d_in[6];
    const float* W_len      = (const float*)d_in[7];
    const float* b_len      = (const float*)d_in[8];
    const int*   valid_lens = (const int*)d_in[9];

    char* ws = (char*)d_ws;
    const size_t MB = 1024 * 1024;
    ushort* qb      = (ushort*)ws;                    // 64 MB
    ushort* keysT   = (ushort*)(ws + 64 * MB);        // 32 MB
    ushort* valsT   = (ushort*)(ws + 96 * MB);        // 32 MB
    ushort* attnout = keysT;                          // aliases keysT+valsT
    ushort* wq = (ushort*)(ws + 128 * MB);            // 5 x 512 KB consecutive
    ushort* wk = wq + 262144;
    ushort* wv = wk + 262144;
    ushort* wo = wv + 262144;
    ushort* wl = wo + 262144;
    ushort* t1  = wl + 262144;                        // 4 Mi elems (8 MB)
    ushort* k1  = t1 + 4194304;
    ushort* v1T = k1 + 4194304;

    const float alpha_q = 0.044194173824159216f;      // 1/sqrt(512)
    dim3 blk(256);

    // all 5 weights -> bf16 in one launch
    cvt_w<<<1280, blk, 0, stream>>>(W_q, W_k, W_v, W_o, W_len, wq);

    // transpose+convert keys/values: [b][1024][512] f32 -> [b][512][1024] bf16
    transpose_cvt<<<dim3(32, 16, 32), blk, 0, stream>>>(keys,   keysT, LVc, Dc);
    transpose_cvt<<<dim3(32, 16, 32), blk, 0, stream>>>(values, valsT, LVc, Dc);

    // k path: t1 = W_len @ keys + b_len ; k1 = t1 @ W_k^T
    gemm_bt<1, true, 0, false><<<dim3(4, 2, 32), blk, 0, stream>>>(
        wl, keysT, t1, b_len, 256, 512, 1024, 1.f, 0, 524288, 131072, 0);
    gemm_bt<1, false, 1, false><<<dim3(256), blk, 0, stream>>>(
        t1, wk, k1, nullptr, 8192, 512, 512, 1.f, 0, 0, 0, 8);

    // v path: t1 = W_len @ values + b_len ; v1T = (t1 @ W_v^T)^T per batch
    gemm_bt<1, true, 0, false><<<dim3(4, 2, 32), blk, 0, stream>>>(
        wl, valsT, t1, b_len, 256, 512, 1024, 1.f, 0, 524288, 131072, 0);
    gemm_bt<2, false, 1, false><<<dim3(256), blk, 0, stream>>>(
        t1, wv, v1T, nullptr, 8192, 512, 512, 1.f, 0, 0, 0, 8);

    // q path: project directly from fp32 queries (cvt fused into staging)
    gemm_bt<1, false, 1, true><<<dim3(2048), blk, 0, stream>>>(
        queries, wq, qb, nullptr, 65536, 512, 512, alpha_q, 0, 0, 0, 64);

    // attention (overwrites keysT/valsT region with attn_out)
    attn_mfma<<<dim3(1024), blk, 0, stream>>>(qb, k1, v1T, valid_lens, attnout);

    // output projection -> fp32 d_out
    gemm_bt<0, false, 1, false><<<dim3(2048), blk, 0, stream>>>(
        attnout, wo, d_out, nullptr, 65536, 512, 512, 1.f, 0, 0, 0, 64);
}

// Round 6
// 357.411 us; speedup vs baseline: 1.2548x; 1.2548x over previous
//
#include <hip/hip_runtime.h>
#include <math.h>

#define Bc  32
#define Hc  8
#define LQc 256
#define LVc 1024
#define Dc  512

typedef short bf16x8 __attribute__((ext_vector_type(8)));
typedef float f32x4  __attribute__((ext_vector_type(4)));

__device__ __forceinline__ unsigned short f2bf(float x) {   // RNE fp32->bf16
    unsigned u = __builtin_bit_cast(unsigned, x);
    u = (u + 0x7fffu + ((u >> 16) & 1u)) >> 16;
    return (unsigned short)u;
}

__device__ __forceinline__ void gload16(const ushort* g, ushort* l) {
    __builtin_amdgcn_global_load_lds(
        (const __attribute__((address_space(1))) unsigned*)g,
        (__attribute__((address_space(3))) unsigned*)l, 16, 0, 0);
}

// ---------------------------------------------------------------------------
// All 5 weight matrices (each 262144 floats) -> bf16, consecutive dst regions
// ---------------------------------------------------------------------------
__global__ __launch_bounds__(256) void cvt_w(const float* __restrict__ a,
                                             const float* __restrict__ b,
                                             const float* __restrict__ c,
                                             const float* __restrict__ d,
                                             const float* __restrict__ e,
                                             ushort* __restrict__ out) {
    const int i = blockIdx.x * 256 + threadIdx.x;    // [0, 327680)
    const int t = i >> 16, j = i & 65535;
    const float* src = (t == 0) ? a : (t == 1) ? b : (t == 2) ? c : (t == 3) ? d : e;
    float4 v = ((const float4*)src)[j];
    ushort4 o;
    o.x = f2bf(v.x); o.y = f2bf(v.y); o.z = f2bf(v.z); o.w = f2bf(v.w);
    ((ushort4*)(out + (size_t)t * 262144))[j] = o;
}

// ---------------------------------------------------------------------------
// fp32 -> bf16 elementwise convert (vectorized float4 / ushort4)
// ---------------------------------------------------------------------------
__global__ __launch_bounds__(256) void cvt_bf16(const float* __restrict__ in,
                                                ushort* __restrict__ out, int n4) {
    int i = blockIdx.x * 256 + threadIdx.x;
    const int stride = gridDim.x * 256;
    for (; i < n4; i += stride) {
        float4 v = ((const float4*)in)[i];
        ushort4 o;
        o.x = f2bf(v.x); o.y = f2bf(v.y); o.z = f2bf(v.z); o.w = f2bf(v.w);
        ((ushort4*)out)[i] = o;
    }
}

// ---------------------------------------------------------------------------
// fp32 [b][L][D] -> bf16 [b][D][L] transpose+convert, 32x32 LDS tiles
// ---------------------------------------------------------------------------
__global__ __launch_bounds__(256) void transpose_cvt(const float* __restrict__ in,
                                                     ushort* __restrict__ out,
                                                     int L, int D) {
    __shared__ float t[32][33];
    const int b = blockIdx.z;
    const int l0 = blockIdx.x * 32, d0 = blockIdx.y * 32;
    in  += (size_t)b * L * D;
    out += (size_t)b * L * D;
    const int r = threadIdx.x >> 5, c = threadIdx.x & 31;
#pragma unroll
    for (int i = 0; i < 4; i++)
        t[r + 8 * i][c] = in[(size_t)(l0 + r + 8 * i) * D + d0 + c];
    __syncthreads();
#pragma unroll
    for (int i = 0; i < 4; i++)
        out[(size_t)(d0 + r + 8 * i) * L + l0 + c] = f2bf(t[c][r + 8 * i]);
}

// ---------------------------------------------------------------------------
// C[m,n] = alpha * sum_k A[m,k]*B[n,k] (+ bias[m])      (bf16 in, f32 accum)
// 128x128 tile, BK=32, 4 waves (2x2), 4x4 16x16x32 frags per wave.
// (R4-proven version: linear LDS, coalesced 4-lane-per-row staging.)
// STORE: 0 = f32 row-major, 1 = bf16 row-major, 2 = bf16 transposed with
//        256-row batches: out[(m>>8)][n][m&255]  (for v1^T)
// SWIZ:  1 = 1D grid, XCD-grouped decode
// ---------------------------------------------------------------------------
template <int STORE, bool BIAS, int SWIZ>
__global__ __launch_bounds__(256) void gemm_bt(const ushort* __restrict__ A,
                                               const ushort* __restrict__ B,
                                               void* __restrict__ Cv,
                                               const float* __restrict__ bias,
                                               int M, int N, int K, float alpha,
                                               long sA, long sB, long sC,
                                               int byPerXcd) {
    __shared__ ushort As[128 * 32];
    __shared__ ushort Bs[128 * 32];
    const int z = blockIdx.z;
    A += (size_t)z * sA;
    B += (size_t)z * sB;
    float*  Cf = (float*)Cv  + (size_t)z * sC;
    ushort* Ch = (ushort*)Cv + (size_t)z * sC;

    int bm, bn;
    if constexpr (SWIZ) {
        const int bid = blockIdx.x;
        const int xcd = bid & 7, slot = bid >> 3;
        bm = (xcd * byPerXcd + (slot >> 2)) * 128;
        bn = (slot & 3) * 128;
    } else {
        bm = blockIdx.y * 128;
        bn = blockIdx.x * 128;
    }
    const int tid = threadIdx.x;
    const int wave = tid >> 6, l = tid & 63;
    const int wm = (wave >> 1) * 64, wn = (wave & 1) * 64;
    const int l15 = l & 15, lh = l >> 4;

    f32x4 acc[4][4];
#pragma unroll
    for (int m = 0; m < 4; m++)
#pragma unroll
        for (int n = 0; n < 4; n++) acc[m][n] = (f32x4){0.f, 0.f, 0.f, 0.f};

    const int srow = tid >> 2, scol = (tid & 3) * 8;
    ushort* ldsA = As + (wave * 16) * 32;
    ushort* ldsB = Bs + (wave * 16) * 32;
    const ushort* gA = A + (size_t)(bm + srow) * K + scol;
    const ushort* gB = B + (size_t)(bn + srow) * K + scol;

    for (int k0 = 0; k0 < K; k0 += 32) {
        gload16(gA + k0, ldsA);
        gload16(gA + k0 + (size_t)64 * K, ldsA + 64 * 32);
        gload16(gB + k0, ldsB);
        gload16(gB + k0 + (size_t)64 * K, ldsB + 64 * 32);
        __syncthreads();
        bf16x8 af[4], bfr[4];
#pragma unroll
        for (int m = 0; m < 4; m++)
            af[m] = *(const bf16x8*)&As[(wm + m * 16 + l15) * 32 + lh * 8];
#pragma unroll
        for (int n = 0; n < 4; n++)
            bfr[n] = *(const bf16x8*)&Bs[(wn + n * 16 + l15) * 32 + lh * 8];
#pragma unroll
        for (int m = 0; m < 4; m++)
#pragma unroll
            for (int n = 0; n < 4; n++)
                acc[m][n] = __builtin_amdgcn_mfma_f32_16x16x32_bf16(
                    af[m], bfr[n], acc[m][n], 0, 0, 0);
        __syncthreads();
    }

    if constexpr (STORE == 2) {
#pragma unroll
        for (int m = 0; m < 4; m++) {
            const int row0 = bm + wm + m * 16 + lh * 4;
            const int bb = row0 >> 8, q = row0 & 255;
#pragma unroll
            for (int n = 0; n < 4; n++) {
                const int col = bn + wn + n * 16 + l15;
                ushort4 o;
                o.x = f2bf(acc[m][n][0] * alpha);
                o.y = f2bf(acc[m][n][1] * alpha);
                o.z = f2bf(acc[m][n][2] * alpha);
                o.w = f2bf(acc[m][n][3] * alpha);
                *(ushort4*)&Ch[(size_t)bb * N * 256 + (size_t)col * 256 + q] = o;
            }
        }
    } else if constexpr (STORE == 1) {
#pragma unroll
        for (int m = 0; m < 4; m++)
#pragma unroll
            for (int r = 0; r < 4; r++) {
                const int row = bm + wm + m * 16 + lh * 4 + r;
                const float bv = BIAS ? bias[row] : 0.f;
#pragma unroll
                for (int n = 0; n < 4; n++) {
                    const int col = bn + wn + n * 16 + l15;
                    Ch[(size_t)row * N + col] = f2bf(acc[m][n][r] * alpha + bv);
                }
            }
    } else {
#pragma unroll
        for (int m = 0; m < 4; m++)
#pragma unroll
            for (int r = 0; r < 4; r++) {
                const int row = bm + wm + m * 16 + lh * 4 + r;
                const float bv = BIAS ? bias[row] : 0.f;
#pragma unroll
                for (int n = 0; n < 4; n++) {
                    const int col = bn + wn + n * 16 + l15;
                    Cf[(size_t)row * N + col] = acc[m][n][r] * alpha + bv;
                }
            }
    }
}

// ---------------------------------------------------------------------------
// Fused attention v4 = R4's v2 structure + CHUNKED conflict-free LDS.
// Block = (b, h, q-half): q-tile 128 rows. Grid 512 (1D), XCD-decoded
// (each batch's 16 blocks on one XCD -> K/V L2-resident). 4 waves.
// Chunked LDS layout: tile = groups of 16 rows; group g at g*1024B; within a
// group, chunk c (16B-granule column c) at c*256B, row r at r*16B. Lane l
// stages (row = l&15, chunk = l>>4) from a permuted GLOBAL address; LDS dest
// stays linear (global_load_lds rule). Every frag ds_read_b128 then hits
// 1024B contiguous per wave -> zero bank conflicts.
// Phase A: S(128x256) = q @ K^T; stage Q 8KB + K 16KB per k0 -> 128 wave-MFMA.
// Softmax in registers; unnormalized P -> LDS [128][264] bf16 (aliases QK
// staging); row sums -> LDS.
// Phase B: out = P @ V via v1T, 4 d-chunks of 128; stage Vs 8KB per l0.
// q pre-scaled by 1/sqrt(D). LDS 76288 B -> 2 blocks/CU.
// ---------------------------------------------------------------------------
__global__ __launch_bounds__(256, 2) void attn_mfma(const ushort* __restrict__ qb,
                                                    const ushort* __restrict__ k1,
                                                    const ushort* __restrict__ v1T,
                                                    const int* __restrict__ vlen,
                                                    ushort* __restrict__ aout) {
    __shared__ __align__(16) char pool[76288];
    ushort* Qs = (ushort*)pool;              // 8 groups  (8 KB, phase A)
    ushort* Ks = (ushort*)(pool + 8192);     // 16 groups (16 KB, phase A)
    ushort* Ps = (ushort*)pool;              // [128][264] 67584 B (phase B)
    ushort* Vs = (ushort*)(pool + 67584);    // 8 groups  (8 KB, phase B)
    float*  rs = (float*)(pool + 75776);     // [128] row sums

    const int bid = blockIdx.x;
    const int xcd = bid & 7, pos = bid >> 3;      // 64 blocks per XCD
    const int b = xcd * 4 + (pos >> 4);           // 4 batches per XCD
    const int inner = pos & 15;
    const int h = inner >> 1, qh = inner & 1;
    const int n = b * 8 + h;
    const int q0 = qh * 128;

    const int tid = threadIdx.x, wave = tid >> 6, l = tid & 63;
    const int l15 = l & 15, lh = l >> 4;
    const int vl = vlen[b];

    const ushort* qbase = qb  + ((size_t)n * LQc + q0) * Dc;
    const ushort* kbase = k1  + (size_t)b * LQc * Dc;
    const ushort* vbase = v1T + (size_t)b * LQc * Dc;

    // ---- phase A: scores 128x256 ---------------------------------------
    f32x4 sacc[2][16];
#pragma unroll
    for (int m = 0; m < 2; m++)
#pragma unroll
        for (int fn = 0; fn < 16; fn++) sacc[m][fn] = (f32x4){0.f, 0.f, 0.f, 0.f};

    for (int k0 = 0; k0 < Dc; k0 += 32) {
        // Q: groups wave, wave+4 (rows wave*16+l15, 64+wave*16+l15)
        gload16(qbase + (size_t)(wave * 16 + l15) * Dc + k0 + lh * 8,      Qs + wave * 512);
        gload16(qbase + (size_t)(64 + wave * 16 + l15) * Dc + k0 + lh * 8, Qs + (wave + 4) * 512);
        // K: groups j*4+wave
#pragma unroll
        for (int j = 0; j < 4; j++)
            gload16(kbase + (size_t)((j * 4 + wave) * 16 + l15) * Dc + k0 + lh * 8,
                    Ks + (j * 4 + wave) * 512);
        __syncthreads();
        bf16x8 aq[2];
        aq[0] = *(const bf16x8*)&Qs[(2 * wave + 0) * 512 + lh * 128 + l15 * 8];
        aq[1] = *(const bf16x8*)&Qs[(2 * wave + 1) * 512 + lh * 128 + l15 * 8];
#pragma unroll
        for (int fn = 0; fn < 16; fn++) {
            bf16x8 bk = *(const bf16x8*)&Ks[fn * 512 + lh * 128 + l15 * 8];
            sacc[0][fn] = __builtin_amdgcn_mfma_f32_16x16x32_bf16(aq[0], bk, sacc[0][fn], 0, 0, 0);
            sacc[1][fn] = __builtin_amdgcn_mfma_f32_16x16x32_bf16(aq[1], bk, sacc[1][fn], 0, 0, 0);
        }
        __syncthreads();
    }

    // ---- softmax: wave owns rows [32w, 32w+32) --------------------------
#pragma unroll
    for (int m = 0; m < 2; m++)
#pragma unroll
        for (int r = 0; r < 4; r++) {
            const int rowl = wave * 32 + m * 16 + lh * 4 + r;
            float v[16];
            float rmax = -3.4e38f;
#pragma unroll
            for (int fn = 0; fn < 16; fn++) {
                const int col = fn * 16 + l15;
                float s = sacc[m][fn][r];
                v[fn] = (col < vl) ? s : -1e6f;
                rmax = fmaxf(rmax, v[fn]);
            }
            rmax = fmaxf(rmax, __shfl_xor(rmax, 1));
            rmax = fmaxf(rmax, __shfl_xor(rmax, 2));
            rmax = fmaxf(rmax, __shfl_xor(rmax, 4));
            rmax = fmaxf(rmax, __shfl_xor(rmax, 8));
            float rsum = 0.f;
#pragma unroll
            for (int fn = 0; fn < 16; fn++) {
                v[fn] = __expf(v[fn] - rmax);
                rsum += v[fn];
            }
            rsum += __shfl_xor(rsum, 1);
            rsum += __shfl_xor(rsum, 2);
            rsum += __shfl_xor(rsum, 4);
            rsum += __shfl_xor(rsum, 8);
#pragma unroll
            for (int fn = 0; fn < 16; fn++)
                Ps[rowl * 264 + fn * 16 + l15] = f2bf(v[fn]);
            if (l15 == 0) rs[rowl] = rsum;
        }
    __syncthreads();

    // ---- phase B: out = P @ V, 4 chunks of 128 d-cols --------------------
    for (int d0 = 0; d0 < Dc; d0 += 128) {
        f32x4 o[8][2];
#pragma unroll
        for (int qf = 0; qf < 8; qf++)
#pragma unroll
            for (int df = 0; df < 2; df++) o[qf][df] = (f32x4){0.f, 0.f, 0.f, 0.f};

        for (int l0 = 0; l0 < LQc; l0 += 32) {
            // V: groups wave, wave+4 (rows d0+wave*16+l15, d0+64+wave*16+l15)
            gload16(vbase + (size_t)(d0 + wave * 16 + l15) * LQc + l0 + lh * 8,
                    Vs + wave * 512);
            gload16(vbase + (size_t)(d0 + 64 + wave * 16 + l15) * LQc + l0 + lh * 8,
                    Vs + (wave + 4) * 512);
            __syncthreads();
            bf16x8 vb[2];
            vb[0] = *(const bf16x8*)&Vs[(2 * wave + 0) * 512 + lh * 128 + l15 * 8];
            vb[1] = *(const bf16x8*)&Vs[(2 * wave + 1) * 512 + lh * 128 + l15 * 8];
#pragma unroll
            for (int qf = 0; qf < 8; qf++) {
                bf16x8 pa = *(const bf16x8*)&Ps[(qf * 16 + l15) * 264 + l0 + lh * 8];
                o[qf][0] = __builtin_amdgcn_mfma_f32_16x16x32_bf16(pa, vb[0], o[qf][0], 0, 0, 0);
                o[qf][1] = __builtin_amdgcn_mfma_f32_16x16x32_bf16(pa, vb[1], o[qf][1], 0, 0, 0);
            }
            __syncthreads();
        }
#pragma unroll
        for (int qf = 0; qf < 8; qf++)
#pragma unroll
            for (int r = 0; r < 4; r++) {
                const int rowl = qf * 16 + lh * 4 + r;
                const float rinv = 1.0f / rs[rowl];
#pragma unroll
                for (int df = 0; df < 2; df++) {
                    const int col = d0 + wave * 32 + df * 16 + l15;
                    aout[((size_t)n * LQc + q0 + rowl) * Dc + col] =
                        f2bf(o[qf][df][r] * rinv);
                }
            }
    }
}

// ---------------------------------------------------------------------------
extern "C" void kernel_launch(void* const* d_in, const int* in_sizes, int n_in,
                              void* d_out, int out_size, void* d_ws, size_t ws_size,
                              hipStream_t stream) {
    const float* queries    = (const float*)d_in[0];
    const float* keys       = (const float*)d_in[1];
    const float* values     = (const float*)d_in[2];
    const float* W_q        = (const float*)d_in[3];
    const float* W_k        = (const float*)d_in[4];
    const float* W_v        = (const float*)d_in[5];
    const float* W_o        = (const float*)d_in[6];
    const float* W_len      = (const float*)d_in[7];
    const float* b_len      = (const float*)d_in[8];
    const int*   valid_lens = (const int*)d_in[9];

    char* ws = (char*)d_ws;
    const size_t MB = 1024 * 1024;
    // layout: qb(64M) | r12(64M: keysT+valsT -> qconv -> attn_out) | weights | t1 | k1 | v1T
    ushort* qb      = (ushort*)ws;                    // 64 MB
    ushort* keysT   = (ushort*)(ws + 64 * MB);        // 32 MB
    ushort* valsT   = (ushort*)(ws + 96 * MB);        // 32 MB
    ushort* qconv   = keysT;                          // aliases keysT+valsT (64 MB)
    ushort* attnout = keysT;                          // aliases same region
    ushort* wq = (ushort*)(ws + 128 * MB);            // 5 x 512 KB consecutive
    ushort* wk = wq + 262144;
    ushort* wv = wk + 262144;
    ushort* wo = wv + 262144;
    ushort* wl = wo + 262144;
    ushort* t1  = wl + 262144;                        // 4 Mi elems (8 MB)
    ushort* k1  = t1 + 4194304;
    ushort* v1T = k1 + 4194304;

    const float alpha_q = 0.044194173824159216f;      // 1/sqrt(512)
    dim3 blk(256);

    // all 5 weights -> bf16 in one launch
    cvt_w<<<1280, blk, 0, stream>>>(W_q, W_k, W_v, W_o, W_len, wq);

    // transpose+convert keys/values: [b][1024][512] f32 -> [b][512][1024] bf16
    transpose_cvt<<<dim3(32, 16, 32), blk, 0, stream>>>(keys,   keysT, LVc, Dc);
    transpose_cvt<<<dim3(32, 16, 32), blk, 0, stream>>>(values, valsT, LVc, Dc);

    // k path: t1 = W_len @ keys + b_len ; k1 = t1 @ W_k^T
    gemm_bt<1, true, 0><<<dim3(4, 2, 32), blk, 0, stream>>>(
        wl, keysT, t1, b_len, 256, 512, 1024, 1.f, 0, 524288, 131072, 0);
    gemm_bt<1, false, 1><<<dim3(256), blk, 0, stream>>>(
        t1, wk, k1, nullptr, 8192, 512, 512, 1.f, 0, 0, 0, 8);

    // v path: t1 = W_len @ values + b_len ; v1T = (t1 @ W_v^T)^T per batch
    gemm_bt<1, true, 0><<<dim3(4, 2, 32), blk, 0, stream>>>(
        wl, valsT, t1, b_len, 256, 512, 1024, 1.f, 0, 524288, 131072, 0);
    gemm_bt<2, false, 1><<<dim3(256), blk, 0, stream>>>(
        t1, wv, v1T, nullptr, 8192, 512, 512, 1.f, 0, 0, 0, 8);

    // q path: convert queries, project (scale folded in)
    cvt_bf16<<<2048, blk, 0, stream>>>(queries, qconv, 8388608);
    gemm_bt<1, false, 1><<<dim3(2048), blk, 0, stream>>>(
        qconv, wq, qb, nullptr, 65536, 512, 512, alpha_q, 0, 0, 0, 64);

    // attention (overwrites qconv region with attn_out)
    attn_mfma<<<dim3(512), blk, 0, stream>>>(qb, k1, v1T, valid_lens, attnout);

    // output projection -> fp32 d_out
    gemm_bt<0, false, 1><<<dim3(2048), blk, 0, stream>>>(
        attnout, wo, d_out, nullptr, 65536, 512, 512, 1.f, 0, 0, 0, 64);
}